// Round 15
// baseline (185.323 us; speedup 1.0000x reference)
//
#include <hip/hip_runtime.h>

#define NN 100000
#define NE 1000000
#define D  64
#define CAP 32          // per-node bucket capacity; Poisson(10) ⇒ P(deg>32) ≈ 2e-9/node
#define OVF_CAP 16384

#define FILL_EPT 8                                        // edges per thread
#define FILL_CHUNK (256 * FILL_EPT)                       // 2048
#define FILL_NCHUNK ((NE + FILL_CHUNK - 1) / FILL_CHUNK)  // 489
#define NCVT 12500                                        // cvt blocks: NN*32/256
#define PART_SZ 12500                                     // NN/8

// ======================= bf16 helpers (RNE pack, shift unpack) =======================
__device__ __forceinline__ unsigned bf16rne(float f) {
    unsigned h = __float_as_uint(f);
    return (h + 0x7fffu + ((h >> 16) & 1u)) >> 16;
}
__device__ __forceinline__ void unpack8(uint4 u, float* f) {
    f[0] = __uint_as_float(u.x << 16); f[1] = __uint_as_float(u.x & 0xffff0000u);
    f[2] = __uint_as_float(u.y << 16); f[3] = __uint_as_float(u.y & 0xffff0000u);
    f[4] = __uint_as_float(u.z << 16); f[5] = __uint_as_float(u.z & 0xffff0000u);
    f[6] = __uint_as_float(u.w << 16); f[7] = __uint_as_float(u.w & 0xffff0000u);
}

// ============ merged: bf16 convert (blocks < NCVT) + bucket fill (rest) ============
__global__ __launch_bounds__(256) void k_cvt_fill(const float2* __restrict__ x2,
                                                  unsigned* __restrict__ xb,
                                                  const int* __restrict__ src,
                                                  const int* __restrict__ dst,
                                                  int* __restrict__ cnt,
                                                  int* __restrict__ bucket,
                                                  int* __restrict__ ovf_n,
                                                  int2* __restrict__ ovf) {
    int bid = blockIdx.x;
    if (bid < NCVT) {
        int i = bid * 256 + threadIdx.x;     // NCVT*256 == NN*32 exactly
        unsigned long long v = __builtin_nontemporal_load((const unsigned long long*)&x2[i]);
        float vx = __uint_as_float((unsigned)(v & 0xffffffffu));
        float vy = __uint_as_float((unsigned)(v >> 32));
        xb[i] = bf16rne(vx) | (bf16rne(vy) << 16);
        return;
    }
    bid -= NCVT;
    const int part = bid & 7;
    const int lo = part * PART_SZ, hi = lo + PART_SZ;
    const int base = (bid >> 3) * FILL_CHUNK + threadIdx.x;

    int ds[FILL_EPT], ss[FILL_EPT];
    #pragma unroll
    for (int it = 0; it < FILL_EPT; ++it) {
        int e = base + it * 256;
        int d = (e < NE) ? __builtin_nontemporal_load(&dst[e]) : -1;
        bool m = (d >= lo && d < hi);
        ds[it] = m ? d : -1;
        ss[it] = m ? __builtin_nontemporal_load(&src[e]) : 0;
    }
    #pragma unroll
    for (int it = 0; it < FILL_EPT; ++it) {
        if (ds[it] >= 0) {
            int c = atomicAdd(&cnt[ds[it]], 1);
            if (c < CAP) {
                bucket[ds[it] * CAP + c] = ss[it];
            } else {                                 // ~never
                int i = atomicAdd(ovf_n, 1);
                if (i < OVF_CAP) ovf[i] = make_int2(ss[it], ds[it]);
            }
        }
    }
}

// ======================= propagation (pull, bf16 rows, fp32 accum) =======================
// 8-lane groups x uint4 (16B): one wave-wide load serves 8 rows (1KB) -- half the
// vmem instructions of the 16-lane/uint2 version. Edge list preloaded in <=4
// chunks of 8; src/weight via __shfl(.,k,8).

__device__ __forceinline__ void gather_chunk(const uint4* __restrict__ in4,
                                             int sR, float wR, int m, int l,
                                             float* a0, float* a1, float* a2, float* a3) {
    int k = 0;
    for (; k + 3 < m; k += 4) {
        int   s0 = __shfl(sR, k + 0, 8);
        int   s1 = __shfl(sR, k + 1, 8);
        int   s2 = __shfl(sR, k + 2, 8);
        int   s3 = __shfl(sR, k + 3, 8);
        float w0 = __shfl(wR, k + 0, 8);
        float w1 = __shfl(wR, k + 1, 8);
        float w2 = __shfl(wR, k + 2, 8);
        float w3 = __shfl(wR, k + 3, 8);
        uint4 u0 = in4[(size_t)s0 * 8 + l];
        uint4 u1 = in4[(size_t)s1 * 8 + l];
        uint4 u2 = in4[(size_t)s2 * 8 + l];
        uint4 u3 = in4[(size_t)s3 * 8 + l];
        float r0[8], r1[8], r2[8], r3[8];
        unpack8(u0, r0); unpack8(u1, r1); unpack8(u2, r2); unpack8(u3, r3);
        #pragma unroll
        for (int j = 0; j < 8; ++j) {
            a0[j] = fmaf(w0, r0[j], a0[j]);
            a1[j] = fmaf(w1, r1[j], a1[j]);
            a2[j] = fmaf(w2, r2[j], a2[j]);
            a3[j] = fmaf(w3, r3[j], a3[j]);
        }
    }
    for (; k < m; ++k) {
        int   s0 = __shfl(sR, k, 8);
        float w0 = __shfl(wR, k, 8);
        uint4 u0 = in4[(size_t)s0 * 8 + l];
        float r0[8];
        unpack8(u0, r0);
        #pragma unroll
        for (int j = 0; j < 8; ++j) a0[j] = fmaf(w0, r0[j], a0[j]);
    }
}

__global__ __launch_bounds__(256) void k_gather_bf16(const uint4* __restrict__ in4,
                                                     const int* __restrict__ cnt,
                                                     const int* __restrict__ bucket,
                                                     const int* __restrict__ ovf_n,
                                                     const int2* __restrict__ ovf,
                                                     uint4* __restrict__ out4) {
    const int tid = threadIdx.x;
    const int l = tid & 7;
    const int n = blockIdx.x * 32 + (tid >> 3);   // 3125*32 == NN exactly

    const int cn = cnt[n];
    const int deg = min(cn, CAP);
    const float dn = rsqrtf((float)(cn + 1));

    float a0[8], a1[8], a2[8], a3[8];
    {
        uint4 u = in4[(size_t)n * 8 + l];
        unpack8(u, a0);
        #pragma unroll
        for (int j = 0; j < 8; ++j) { a0[j] *= dn; a1[j] = 0.f; a2[j] = 0.f; a3[j] = 0.f; }
    }

    if (deg > 0) {
        int   i0 = (l < deg) ? l : 0;
        int   sA = bucket[(size_t)n * CAP + i0];
        float wA = rsqrtf((float)(cnt[sA] + 1));
        gather_chunk(in4, sA, wA, min(deg, 8), l, a0, a1, a2, a3);
        if (deg > 8) {                      // ~67% of nodes
            int   i1 = (8 + l < deg) ? (8 + l) : 0;
            int   sB = bucket[(size_t)n * CAP + i1];
            float wB = rsqrtf((float)(cnt[sB] + 1));
            gather_chunk(in4, sB, wB, min(deg - 8, 8), l, a0, a1, a2, a3);
            if (deg > 16) {                 // ~3%
                int   i2 = (16 + l < deg) ? (16 + l) : 0;
                int   sC = bucket[(size_t)n * CAP + i2];
                float wC = rsqrtf((float)(cnt[sC] + 1));
                gather_chunk(in4, sC, wC, min(deg - 16, 8), l, a0, a1, a2, a3);
                if (deg > 24) {             // ~0.02%
                    int   i3 = (24 + l < deg) ? (24 + l) : 0;
                    int   sD = bucket[(size_t)n * CAP + i3];
                    float wD = rsqrtf((float)(cnt[sD] + 1));
                    gather_chunk(in4, sD, wD, min(deg - 24, 8), l, a0, a1, a2, a3);
                }
            }
        }
    }

    // inline overflow fixup (ovf_n is ~always 0; one hot scalar load)
    int m = *ovf_n;
    if (m > 0) {
        if (m > OVF_CAP) m = OVF_CAP;
        for (int i = 0; i < m; ++i) {
            int2 p = ovf[i];
            if (p.y == n) {
                float w = rsqrtf((float)(cnt[p.x] + 1));
                uint4 u = in4[(size_t)p.x * 8 + l];
                float r[8];
                unpack8(u, r);
                #pragma unroll
                for (int j = 0; j < 8; ++j) a0[j] = fmaf(w, r[j], a0[j]);
            }
        }
    }

    float f[8];
    #pragma unroll
    for (int j = 0; j < 8; ++j) f[j] = dn * ((a0[j] + a1[j]) + (a2[j] + a3[j]));
    uint4 o;
    o.x = bf16rne(f[0]) | (bf16rne(f[1]) << 16);
    o.y = bf16rne(f[2]) | (bf16rne(f[3]) << 16);
    o.z = bf16rne(f[4]) | (bf16rne(f[5]) << 16);
    o.w = bf16rne(f[6]) | (bf16rne(f[7]) << 16);
    out4[(size_t)n * 8 + l] = o;
}

// ======================= linear: W in registers, readlane row broadcast =======================
__global__ __launch_bounds__(256) void k_linear_reg(const unsigned short* __restrict__ inb,
                                                    const float* __restrict__ W,
                                                    const float* __restrict__ bias,
                                                    float* __restrict__ out) {
    const int lane = threadIdx.x & 63;
    const int wid  = (blockIdx.x * blockDim.x + threadIdx.x) >> 6;
    const int nw   = (gridDim.x * blockDim.x) >> 6;

    float w[64];
    const float4* W4 = (const float4*)W;
    #pragma unroll
    for (int i = 0; i < 16; ++i) {
        float4 q = W4[lane * 16 + i];
        w[4 * i + 0] = q.x; w[4 * i + 1] = q.y;
        w[4 * i + 2] = q.z; w[4 * i + 3] = q.w;
    }
    const float bo = bias[lane];

    for (int n = wid; n < NN; n += nw) {
        unsigned short rh = __builtin_nontemporal_load(&inb[(size_t)n * 64 + lane]);
        int rli = (int)((unsigned)rh << 16);
        float y0 = bo, y1 = 0.f;
        #pragma unroll
        for (int i = 0; i < 64; i += 2) {
            y0 = fmaf(__int_as_float(__builtin_amdgcn_readlane(rli, i)),     w[i],     y0);
            y1 = fmaf(__int_as_float(__builtin_amdgcn_readlane(rli, i + 1)), w[i + 1], y1);
        }
        __builtin_nontemporal_store(y0 + y1, &out[(size_t)n * 64 + lane]);
    }
}

// ======================= fallback path (atomic scatter, fp32) =======================

__global__ void k_init_deg(float* __restrict__ deg) {
    int n = blockIdx.x * blockDim.x + threadIdx.x;
    if (n < NN) deg[n] = 1.0f;
}
__global__ void k_count_deg(const int* __restrict__ dst, float* __restrict__ deg) {
    int e = blockIdx.x * blockDim.x + threadIdx.x;
    if (e < NE) atomicAdd(&deg[dst[e]], 1.0f);
}
__global__ void k_dinv_f(float* __restrict__ deg) {
    int n = blockIdx.x * blockDim.x + threadIdx.x;
    if (n < NN) deg[n] = rsqrtf(deg[n]);
}
__global__ void k_prop_init(const float* __restrict__ in, const float* __restrict__ dinv,
                            float* __restrict__ out) {
    int i = blockIdx.x * blockDim.x + threadIdx.x;
    if (i < NN * D) {
        int n = i >> 6;
        float di = dinv[n];
        out[i] = di * di * in[i];
    }
}
__global__ __launch_bounds__(256) void k_prop_edges(const float* __restrict__ in,
                                                    const int* __restrict__ src,
                                                    const int* __restrict__ dst,
                                                    const float* __restrict__ dinv,
                                                    float* __restrict__ out) {
    int t = blockIdx.x * blockDim.x + threadIdx.x;
    int e = t >> 6, f = t & 63;
    if (e < NE) {
        int s = src[e], d = dst[e];
        float w = dinv[s] * dinv[d];
        atomicAdd(&out[d * D + f], w * in[s * D + f]);
    }
}
__global__ __launch_bounds__(256) void k_linear(const float* __restrict__ in,
                                                const float* __restrict__ W,
                                                const float* __restrict__ bias,
                                                float* __restrict__ out) {
    __shared__ float Wt[64 * 65];
    __shared__ float rows[4][64];
    const int tid = threadIdx.x;
    for (int m = tid; m < 64 * 64; m += 256) {
        int o = m >> 6, i = m & 63;
        Wt[i * 65 + o] = W[m];
    }
    __syncthreads();
    const int wave = tid >> 6, lane = tid & 63;
    const float bo = bias[lane];
    for (int base = blockIdx.x * 4; base < NN; base += gridDim.x * 4) {
        int n = base + wave;
        if (n < NN) {
            rows[wave][lane] = in[n * D + lane];
            float acc = bo;
            #pragma unroll
            for (int i = 0; i < 64; ++i)
                acc = fmaf(rows[wave][i], Wt[i * 65 + lane], acc);
            out[n * D + lane] = acc;
        }
    }
}

// ======================= launch =======================

extern "C" void kernel_launch(void* const* d_in, const int* in_sizes, int n_in,
                              void* d_out, int out_size, void* d_ws, size_t ws_size,
                              hipStream_t stream) {
    const float* x   = (const float*)d_in[0];
    const int*   ei  = (const int*)d_in[1];
    const float* W   = (const float*)d_in[2];
    const float* b   = (const float*)d_in[3];
    float* out = (float*)d_out;

    const int* src = ei;        // edge_index[0]
    const int* dst = ei + NE;   // edge_index[1]

    char* ws = (char*)d_ws;
    size_t off = 0;
    auto take = [&](size_t bytes) -> char* {
        char* p = ws + off;
        off = (off + bytes + 255) & ~(size_t)255;
        return p;
    };

    int*      cnt    = (int*)take((size_t)NN * 4);
    int*      ovf_n  = (int*)take(256);                        // adjacent to cnt: one memset
    float*    dinv   = (float*)take((size_t)NN * 4);           // fallback path only
    int2*     ovf    = (int2*)take((size_t)OVF_CAP * 8);
    unsigned* P      = (unsigned*)take((size_t)NN * 32 * 4);   // bf16 buffer (12.8 MB)
    unsigned* Q      = (unsigned*)take((size_t)NN * 32 * 4);   // bf16 buffer (12.8 MB)
    int*      bucket = (int*)take((size_t)NN * CAP * 4);
    float*    buf    = (float*)P;   // fallback fp32 buffer: spans P+Q (25.6 MB, contiguous)
    const bool use_bucket = (off <= ws_size);

    const int B = 256;
    const int gridE1 = (NE + B - 1) / B;   // 3907
    const int gridN1 = (NN + B - 1) / B;   // 391
    const int gridNW = NN / 32;            // 3125 (8-lane groups, 32 nodes/block)

    if (use_bucket) {
        size_t zlen = (size_t)((char*)ovf_n - (char*)cnt) + 256;
        hipMemsetAsync(cnt, 0, zlen, stream);
        k_cvt_fill<<<NCVT + FILL_NCHUNK * 8, B, 0, stream>>>((const float2*)x, P,
                                                             src, dst, cnt, bucket,
                                                             ovf_n, ovf);
        // hop1: P -> Q
        k_gather_bf16<<<gridNW, B, 0, stream>>>((const uint4*)P, cnt, bucket, ovf_n, ovf, (uint4*)Q);
        // hop2: Q -> P
        k_gather_bf16<<<gridNW, B, 0, stream>>>((const uint4*)Q, cnt, bucket, ovf_n, ovf, (uint4*)P);
        // hop3: P -> Q
        k_gather_bf16<<<gridNW, B, 0, stream>>>((const uint4*)P, cnt, bucket, ovf_n, ovf, (uint4*)Q);
        // linear: Q -> out (fp32 W, fp32 accum)
        k_linear_reg<<<1024, B, 0, stream>>>((const unsigned short*)Q, W, b, out);
    } else {
        const int gridF = (NN * D + B - 1) / B;
        const int gridEW = (NE * 64) / B;
        k_init_deg <<<gridN1, B, 0, stream>>>(dinv);
        k_count_deg<<<gridE1, B, 0, stream>>>(dst, dinv);
        k_dinv_f   <<<gridN1, B, 0, stream>>>(dinv);
        k_prop_init <<<gridF, B, 0, stream>>>(x, dinv, buf);
        k_prop_edges<<<gridEW, B, 0, stream>>>(x, src, dst, dinv, buf);
        k_prop_init <<<gridF, B, 0, stream>>>(buf, dinv, out);
        k_prop_edges<<<gridEW, B, 0, stream>>>(buf, src, dst, dinv, out);
        k_prop_init <<<gridF, B, 0, stream>>>(out, dinv, buf);
        k_prop_edges<<<gridEW, B, 0, stream>>>(out, src, dst, dinv, buf);
        k_linear<<<NN / 4, B, 0, stream>>>(buf, W, b, out);
    }
}

// Round 16
// 181.699 us; speedup vs baseline: 1.0199x; 1.0199x over previous
//
#include <hip/hip_runtime.h>

#define NN 100000
#define NE 1000000
#define D  64
#define CAP 32          // per-node bucket capacity; Poisson(10) ⇒ P(deg>32) ≈ 2e-9/node
#define OVF_CAP 16384

#define FILL_EPT 8                                        // edges per thread
#define FILL_CHUNK (256 * FILL_EPT)                       // 2048
#define FILL_NCHUNK ((NE + FILL_CHUNK - 1) / FILL_CHUNK)  // 489
#define NFILL (FILL_NCHUNK * 8)                           // 3912 fill blocks
#define NCVT 12500                                        // cvt blocks: NN*32/256
#define PART_SZ 12500                                     // NN/8

// ======================= bf16 helpers (RNE pack, shift unpack) =======================
__device__ __forceinline__ unsigned bf16rne(float f) {
    unsigned h = __float_as_uint(f);
    return (h + 0x7fffu + ((h >> 16) & 1u)) >> 16;
}
__device__ __forceinline__ uint2 pack4(float4 v) {
    uint2 o;
    o.x = bf16rne(v.x) | (bf16rne(v.y) << 16);
    o.y = bf16rne(v.z) | (bf16rne(v.w) << 16);
    return o;
}
__device__ __forceinline__ float4 unpack4(uint2 u) {
    float4 f;
    f.x = __uint_as_float(u.x << 16);
    f.y = __uint_as_float(u.x & 0xffff0000u);
    f.z = __uint_as_float(u.y << 16);
    f.w = __uint_as_float(u.y & 0xffff0000u);
    return f;
}

// ============ merged: bucket fill (blocks < NFILL) + bf16 convert (rest) ============
// FILL blocks dispatched FIRST: latency-bound fill waves get resident early, and
// the BW-bound cvt blocks backfill idle issue slots while fill stalls on fabric
// atomics (r14 had cvt first -> fill started only after cvt drained: no overlap).
__global__ __launch_bounds__(256) void k_cvt_fill(const float2* __restrict__ x2,
                                                  unsigned* __restrict__ xb,
                                                  const int* __restrict__ src,
                                                  const int* __restrict__ dst,
                                                  int* __restrict__ cnt,
                                                  int* __restrict__ bucket,
                                                  int* __restrict__ ovf_n,
                                                  int2* __restrict__ ovf) {
    int bid = blockIdx.x;
    if (bid >= NFILL) {
        int i = (bid - NFILL) * 256 + threadIdx.x;   // NCVT*256 == NN*32 exactly
        unsigned long long v = __builtin_nontemporal_load((const unsigned long long*)&x2[i]);
        float vx = __uint_as_float((unsigned)(v & 0xffffffffu));
        float vy = __uint_as_float((unsigned)(v >> 32));
        xb[i] = bf16rne(vx) | (bf16rne(vy) << 16);
        return;
    }
    const int part = bid & 7;
    const int lo = part * PART_SZ, hi = lo + PART_SZ;
    const int base = (bid >> 3) * FILL_CHUNK + threadIdx.x;

    int ds[FILL_EPT], ss[FILL_EPT];
    #pragma unroll
    for (int it = 0; it < FILL_EPT; ++it) {
        int e = base + it * 256;
        int d = (e < NE) ? __builtin_nontemporal_load(&dst[e]) : -1;
        bool m = (d >= lo && d < hi);
        ds[it] = m ? d : -1;
        ss[it] = m ? __builtin_nontemporal_load(&src[e]) : 0;
    }
    #pragma unroll
    for (int it = 0; it < FILL_EPT; ++it) {
        if (ds[it] >= 0) {
            int c = atomicAdd(&cnt[ds[it]], 1);
            if (c < CAP) {
                bucket[ds[it] * CAP + c] = ss[it];
            } else {                                 // ~never
                int i = atomicAdd(ovf_n, 1);
                if (i < OVF_CAP) ovf[i] = make_int2(ss[it], ds[it]);
            }
        }
    }
}

// ======================= propagation (pull, bf16 rows, fp32 accum) =======================
// 16-lane groups x uint2 (r14 structure; r15's 8-lane/uint4 regressed). Main loop
// 8-DEEP: 8 independent row loads in flight before any FMA -> 1-2 latency
// exposures for deg<=16 (97% of nodes) instead of ~3 at 4-deep.

__global__ __launch_bounds__(256) void k_gather_bf16(const uint2* __restrict__ in2,
                                                     const int* __restrict__ cnt,
                                                     const int* __restrict__ bucket,
                                                     const int* __restrict__ ovf_n,
                                                     const int2* __restrict__ ovf,
                                                     uint2* __restrict__ out2) {
    const int tid = threadIdx.x;
    const int l = tid & 15;
    const int n = blockIdx.x * 16 + (tid >> 4);   // 6250*16 == NN exactly

    const int cn = cnt[n];
    const int deg = min(cn, CAP);
    const float dn = rsqrtf((float)(cn + 1));

    float4 a0 = unpack4(in2[(size_t)n * 16 + l]);
    a0.x *= dn; a0.y *= dn; a0.z *= dn; a0.w *= dn;
    float4 a1 = make_float4(0.f, 0.f, 0.f, 0.f);
    float4 a2 = make_float4(0.f, 0.f, 0.f, 0.f);
    float4 a3 = make_float4(0.f, 0.f, 0.f, 0.f);

    if (deg > 0) {
        int   iA = (l < deg) ? l : 0;
        int   sA = bucket[(size_t)n * CAP + iA];
        float wA = rsqrtf((float)(cnt[sA] + 1));
        const int kmax = deg < 16 ? deg : 16;
        int k = 0;
        for (; k + 7 < kmax; k += 8) {           // 8 loads in flight
            int s[8]; float w[8]; uint2 u[8];
            #pragma unroll
            for (int j = 0; j < 8; ++j) {
                s[j] = __shfl(sA, k + j, 16);
                w[j] = __shfl(wA, k + j, 16);
            }
            #pragma unroll
            for (int j = 0; j < 8; ++j) u[j] = in2[(size_t)s[j] * 16 + l];
            #pragma unroll
            for (int j = 0; j < 8; ++j) {
                float4 r = unpack4(u[j]);
                float4* a = (j & 3) == 0 ? &a0 : (j & 3) == 1 ? &a1 : (j & 3) == 2 ? &a2 : &a3;
                a->x = fmaf(w[j], r.x, a->x); a->y = fmaf(w[j], r.y, a->y);
                a->z = fmaf(w[j], r.z, a->z); a->w = fmaf(w[j], r.w, a->w);
            }
        }
        for (; k + 3 < kmax; k += 4) {           // 4 in flight
            int s[4]; float w[4]; uint2 u[4];
            #pragma unroll
            for (int j = 0; j < 4; ++j) {
                s[j] = __shfl(sA, k + j, 16);
                w[j] = __shfl(wA, k + j, 16);
            }
            #pragma unroll
            for (int j = 0; j < 4; ++j) u[j] = in2[(size_t)s[j] * 16 + l];
            #pragma unroll
            for (int j = 0; j < 4; ++j) {
                float4 r = unpack4(u[j]);
                float4* a = j == 0 ? &a0 : j == 1 ? &a1 : j == 2 ? &a2 : &a3;
                a->x = fmaf(w[j], r.x, a->x); a->y = fmaf(w[j], r.y, a->y);
                a->z = fmaf(w[j], r.z, a->z); a->w = fmaf(w[j], r.w, a->w);
            }
        }
        for (; k < kmax; ++k) {
            int   s0 = __shfl(sA, k, 16);
            float w0 = __shfl(wA, k, 16);
            float4 r0 = unpack4(in2[(size_t)s0 * 16 + l]);
            a0.x = fmaf(w0, r0.x, a0.x); a0.y = fmaf(w0, r0.y, a0.y);
            a0.z = fmaf(w0, r0.z, a0.z); a0.w = fmaf(w0, r0.w, a0.w);
        }
        if (deg > 16) {   // ~3% of nodes
            int   iB = (16 + l < deg) ? (16 + l) : 0;
            int   sB = bucket[(size_t)n * CAP + iB];
            float wB = rsqrtf((float)(cnt[sB] + 1));
            const int k2max = deg - 16;
            int k2 = 0;
            for (; k2 + 1 < k2max; k2 += 2) {
                int   s0 = __shfl(sB, k2 + 0, 16);
                int   s1 = __shfl(sB, k2 + 1, 16);
                float w0 = __shfl(wB, k2 + 0, 16);
                float w1 = __shfl(wB, k2 + 1, 16);
                float4 r0 = unpack4(in2[(size_t)s0 * 16 + l]);
                float4 r1 = unpack4(in2[(size_t)s1 * 16 + l]);
                a1.x = fmaf(w0, r0.x, a1.x); a1.y = fmaf(w0, r0.y, a1.y);
                a1.z = fmaf(w0, r0.z, a1.z); a1.w = fmaf(w0, r0.w, a1.w);
                a2.x = fmaf(w1, r1.x, a2.x); a2.y = fmaf(w1, r1.y, a2.y);
                a2.z = fmaf(w1, r1.z, a2.z); a2.w = fmaf(w1, r1.w, a2.w);
            }
            if (k2 < k2max) {
                int   s0 = __shfl(sB, k2, 16);
                float w0 = __shfl(wB, k2, 16);
                float4 r0 = unpack4(in2[(size_t)s0 * 16 + l]);
                a3.x = fmaf(w0, r0.x, a3.x); a3.y = fmaf(w0, r0.y, a3.y);
                a3.z = fmaf(w0, r0.z, a3.z); a3.w = fmaf(w0, r0.w, a3.w);
            }
        }
    }

    // inline overflow fixup (ovf_n is ~always 0; one hot scalar load)
    int m = *ovf_n;
    if (m > 0) {
        if (m > OVF_CAP) m = OVF_CAP;
        for (int i = 0; i < m; ++i) {
            int2 p = ovf[i];
            if (p.y == n) {
                float w = rsqrtf((float)(cnt[p.x] + 1));
                float4 r = unpack4(in2[(size_t)p.x * 16 + l]);
                a0.x = fmaf(w, r.x, a0.x); a0.y = fmaf(w, r.y, a0.y);
                a0.z = fmaf(w, r.z, a0.z); a0.w = fmaf(w, r.w, a0.w);
            }
        }
    }

    float4 r;
    r.x = dn * ((a0.x + a1.x) + (a2.x + a3.x));
    r.y = dn * ((a0.y + a1.y) + (a2.y + a3.y));
    r.z = dn * ((a0.z + a1.z) + (a2.z + a3.z));
    r.w = dn * ((a0.w + a1.w) + (a2.w + a3.w));
    out2[(size_t)n * 16 + l] = pack4(r);
}

// ======================= linear: W in registers, readlane row broadcast =======================
__global__ __launch_bounds__(256) void k_linear_reg(const unsigned short* __restrict__ inb,
                                                    const float* __restrict__ W,
                                                    const float* __restrict__ bias,
                                                    float* __restrict__ out) {
    const int lane = threadIdx.x & 63;
    const int wid  = (blockIdx.x * blockDim.x + threadIdx.x) >> 6;
    const int nw   = (gridDim.x * blockDim.x) >> 6;

    float w[64];
    const float4* W4 = (const float4*)W;
    #pragma unroll
    for (int i = 0; i < 16; ++i) {
        float4 q = W4[lane * 16 + i];
        w[4 * i + 0] = q.x; w[4 * i + 1] = q.y;
        w[4 * i + 2] = q.z; w[4 * i + 3] = q.w;
    }
    const float bo = bias[lane];

    for (int n = wid; n < NN; n += nw) {
        unsigned short rh = __builtin_nontemporal_load(&inb[(size_t)n * 64 + lane]);
        int rli = (int)((unsigned)rh << 16);
        float y0 = bo, y1 = 0.f;
        #pragma unroll
        for (int i = 0; i < 64; i += 2) {
            y0 = fmaf(__int_as_float(__builtin_amdgcn_readlane(rli, i)),     w[i],     y0);
            y1 = fmaf(__int_as_float(__builtin_amdgcn_readlane(rli, i + 1)), w[i + 1], y1);
        }
        __builtin_nontemporal_store(y0 + y1, &out[(size_t)n * 64 + lane]);
    }
}

// ======================= fallback path (atomic scatter, fp32) =======================

__global__ void k_init_deg(float* __restrict__ deg) {
    int n = blockIdx.x * blockDim.x + threadIdx.x;
    if (n < NN) deg[n] = 1.0f;
}
__global__ void k_count_deg(const int* __restrict__ dst, float* __restrict__ deg) {
    int e = blockIdx.x * blockDim.x + threadIdx.x;
    if (e < NE) atomicAdd(&deg[dst[e]], 1.0f);
}
__global__ void k_dinv_f(float* __restrict__ deg) {
    int n = blockIdx.x * blockDim.x + threadIdx.x;
    if (n < NN) deg[n] = rsqrtf(deg[n]);
}
__global__ void k_prop_init(const float* __restrict__ in, const float* __restrict__ dinv,
                            float* __restrict__ out) {
    int i = blockIdx.x * blockDim.x + threadIdx.x;
    if (i < NN * D) {
        int n = i >> 6;
        float di = dinv[n];
        out[i] = di * di * in[i];
    }
}
__global__ __launch_bounds__(256) void k_prop_edges(const float* __restrict__ in,
                                                    const int* __restrict__ src,
                                                    const int* __restrict__ dst,
                                                    const float* __restrict__ dinv,
                                                    float* __restrict__ out) {
    int t = blockIdx.x * blockDim.x + threadIdx.x;
    int e = t >> 6, f = t & 63;
    if (e < NE) {
        int s = src[e], d = dst[e];
        float w = dinv[s] * dinv[d];
        atomicAdd(&out[d * D + f], w * in[s * D + f]);
    }
}
__global__ __launch_bounds__(256) void k_linear(const float* __restrict__ in,
                                                const float* __restrict__ W,
                                                const float* __restrict__ bias,
                                                float* __restrict__ out) {
    __shared__ float Wt[64 * 65];
    __shared__ float rows[4][64];
    const int tid = threadIdx.x;
    for (int m = tid; m < 64 * 64; m += 256) {
        int o = m >> 6, i = m & 63;
        Wt[i * 65 + o] = W[m];
    }
    __syncthreads();
    const int wave = tid >> 6, lane = tid & 63;
    const float bo = bias[lane];
    for (int base = blockIdx.x * 4; base < NN; base += gridDim.x * 4) {
        int n = base + wave;
        if (n < NN) {
            rows[wave][lane] = in[n * D + lane];
            float acc = bo;
            #pragma unroll
            for (int i = 0; i < 64; ++i)
                acc = fmaf(rows[wave][i], Wt[i * 65 + lane], acc);
            out[n * D + lane] = acc;
        }
    }
}

// ======================= launch =======================

extern "C" void kernel_launch(void* const* d_in, const int* in_sizes, int n_in,
                              void* d_out, int out_size, void* d_ws, size_t ws_size,
                              hipStream_t stream) {
    const float* x   = (const float*)d_in[0];
    const int*   ei  = (const int*)d_in[1];
    const float* W   = (const float*)d_in[2];
    const float* b   = (const float*)d_in[3];
    float* out = (float*)d_out;

    const int* src = ei;        // edge_index[0]
    const int* dst = ei + NE;   // edge_index[1]

    char* ws = (char*)d_ws;
    size_t off = 0;
    auto take = [&](size_t bytes) -> char* {
        char* p = ws + off;
        off = (off + bytes + 255) & ~(size_t)255;
        return p;
    };

    int*      cnt    = (int*)take((size_t)NN * 4);
    int*      ovf_n  = (int*)take(256);                        // adjacent to cnt: one memset
    float*    dinv   = (float*)take((size_t)NN * 4);           // fallback path only
    int2*     ovf    = (int2*)take((size_t)OVF_CAP * 8);
    unsigned* P      = (unsigned*)take((size_t)NN * 32 * 4);   // bf16 buffer (12.8 MB)
    unsigned* Q      = (unsigned*)take((size_t)NN * 32 * 4);   // bf16 buffer (12.8 MB)
    int*      bucket = (int*)take((size_t)NN * CAP * 4);
    float*    buf    = (float*)P;   // fallback fp32 buffer: spans P+Q (25.6 MB, contiguous)
    const bool use_bucket = (off <= ws_size);

    const int B = 256;
    const int gridE1 = (NE + B - 1) / B;   // 3907
    const int gridN1 = (NN + B - 1) / B;   // 391
    const int gridNW = NN / 16;            // 6250

    if (use_bucket) {
        size_t zlen = (size_t)((char*)ovf_n - (char*)cnt) + 256;
        hipMemsetAsync(cnt, 0, zlen, stream);
        // merged fill (first) + convert (backfills)
        k_cvt_fill<<<NFILL + NCVT, B, 0, stream>>>((const float2*)x, P,
                                                   src, dst, cnt, bucket,
                                                   ovf_n, ovf);
        // hop1: P -> Q
        k_gather_bf16<<<gridNW, B, 0, stream>>>((const uint2*)P, cnt, bucket, ovf_n, ovf, (uint2*)Q);
        // hop2: Q -> P
        k_gather_bf16<<<gridNW, B, 0, stream>>>((const uint2*)Q, cnt, bucket, ovf_n, ovf, (uint2*)P);
        // hop3: P -> Q
        k_gather_bf16<<<gridNW, B, 0, stream>>>((const uint2*)P, cnt, bucket, ovf_n, ovf, (uint2*)Q);
        // linear: Q -> out (fp32 W, fp32 accum)
        k_linear_reg<<<1024, B, 0, stream>>>((const unsigned short*)Q, W, b, out);
    } else {
        const int gridF = (NN * D + B - 1) / B;
        const int gridEW = (NE * 64) / B;
        k_init_deg <<<gridN1, B, 0, stream>>>(dinv);
        k_count_deg<<<gridE1, B, 0, stream>>>(dst, dinv);
        k_dinv_f   <<<gridN1, B, 0, stream>>>(dinv);
        k_prop_init <<<gridF, B, 0, stream>>>(x, dinv, buf);
        k_prop_edges<<<gridEW, B, 0, stream>>>(x, src, dst, dinv, buf);
        k_prop_init <<<gridF, B, 0, stream>>>(buf, dinv, out);
        k_prop_edges<<<gridEW, B, 0, stream>>>(buf, src, dst, dinv, out);
        k_prop_init <<<gridF, B, 0, stream>>>(out, dinv, buf);
        k_prop_edges<<<gridEW, B, 0, stream>>>(out, src, dst, dinv, buf);
        k_linear<<<NN / 4, B, 0, stream>>>(buf, W, b, out);
    }
}

// Round 18
// 172.006 us; speedup vs baseline: 1.0774x; 1.0564x over previous
//
#include <hip/hip_runtime.h>

#define NN 100000
#define NE 1000000
#define D  64
#define CAP 32          // per-node bucket capacity; Poisson(10) ⇒ P(deg>32) ≈ 2e-9/node
#define OVF_CAP 16384

#define FILL_EPT 8                                        // edges per thread
#define FILL_CHUNK (256 * FILL_EPT)                       // 2048
#define FILL_NCHUNK ((NE + FILL_CHUNK - 1) / FILL_CHUNK)  // 489
#define PART_SZ 12500                                     // NN/8

// ======================= bf16 helpers (RNE pack, shift unpack) =======================
__device__ __forceinline__ unsigned bf16rne(float f) {
    unsigned h = __float_as_uint(f);
    return (h + 0x7fffu + ((h >> 16) & 1u)) >> 16;
}
__device__ __forceinline__ uint2 pack4(float4 v) {
    uint2 o;
    o.x = bf16rne(v.x) | (bf16rne(v.y) << 16);
    o.y = bf16rne(v.z) | (bf16rne(v.w) << 16);
    return o;
}
__device__ __forceinline__ float4 unpack4(uint2 u) {
    float4 f;
    f.x = __uint_as_float(u.x << 16);
    f.y = __uint_as_float(u.x & 0xffff0000u);
    f.z = __uint_as_float(u.y << 16);
    f.w = __uint_as_float(u.y & 0xffff0000u);
    return f;
}

// ======================= bucket build (round-10 structure: best measured) ==========
__global__ __launch_bounds__(256) void k_fill_bucket(const int* __restrict__ src,
                                                     const int* __restrict__ dst,
                                                     int* __restrict__ cnt,
                                                     int* __restrict__ bucket,
                                                     int* __restrict__ ovf_n,
                                                     int2* __restrict__ ovf) {
    const int part = blockIdx.x & 7;
    const int lo = part * PART_SZ, hi = lo + PART_SZ;
    const int base = (blockIdx.x >> 3) * FILL_CHUNK + threadIdx.x;
    #pragma unroll
    for (int it = 0; it < FILL_EPT; ++it) {
        int e = base + it * 256;
        if (e < NE) {
            int d = __builtin_nontemporal_load(&dst[e]);
            if (d >= lo && d < hi) {
                int s = __builtin_nontemporal_load(&src[e]);
                int c = atomicAdd(&cnt[d], 1);
                if (c < CAP) {
                    bucket[(size_t)d * CAP + c] = s;
                } else {                                 // ~never
                    int i = atomicAdd(ovf_n, 1);
                    if (i < OVF_CAP) ovf[i] = make_int2(s, d);
                }
            }
        }
    }
}

// ============ cvt+linear: P = bf16(x @ W^T)  (S and W commute: S^3(xW^T)=(S^3x)W^T) ====
// wave = node, lane = output col. W[lane][:] in 64 VGPRs; x-row broadcast via readlane.
__global__ __launch_bounds__(256) void k_cvt_linw(const float* __restrict__ x,
                                                  const float* __restrict__ W,
                                                  unsigned short* __restrict__ P) {
    const int lane = threadIdx.x & 63;
    const int wid  = (blockIdx.x * blockDim.x + threadIdx.x) >> 6;
    const int nw   = (gridDim.x * blockDim.x) >> 6;

    float w[64];
    const float4* W4 = (const float4*)W;
    #pragma unroll
    for (int i = 0; i < 16; ++i) {
        float4 q = W4[lane * 16 + i];
        w[4 * i + 0] = q.x; w[4 * i + 1] = q.y;
        w[4 * i + 2] = q.z; w[4 * i + 3] = q.w;
    }

    for (int n = wid; n < NN; n += nw) {
        float xl = __builtin_nontemporal_load(&x[(size_t)n * 64 + lane]);
        int xi = __float_as_int(xl);
        float y0 = 0.f, y1 = 0.f;
        #pragma unroll
        for (int i = 0; i < 64; i += 2) {
            y0 = fmaf(__int_as_float(__builtin_amdgcn_readlane(xi, i)),     w[i],     y0);
            y1 = fmaf(__int_as_float(__builtin_amdgcn_readlane(xi, i + 1)), w[i + 1], y1);
        }
        P[(size_t)n * 64 + lane] = (unsigned short)bf16rne(y0 + y1);
    }
}

// ======================= propagation (pull, bf16 rows, fp32 accum, 4-deep) ==========
// out[n] = dinv[n] * ( dinv[n]*in[n] + sum_{s in N(n)} dinv[s]*in[s] ),
// dinv = rsqrt(cnt+1) on the fly. F32OUT: add bias, write fp32 (final hop).

template <bool F32OUT>
__device__ __forceinline__ void gather_body(const uint2* __restrict__ in2,
                                            const int* __restrict__ cnt,
                                            const int* __restrict__ bucket,
                                            const int* __restrict__ ovf_n,
                                            const int2* __restrict__ ovf,
                                            const float* __restrict__ bias,
                                            uint2* __restrict__ out2,
                                            float4* __restrict__ out4) {
    const int tid = threadIdx.x;
    const int l = tid & 15;
    const int n = blockIdx.x * 16 + (tid >> 4);   // 6250*16 == NN exactly

    const int cn = cnt[n];
    const int deg = min(cn, CAP);
    const float dn = rsqrtf((float)(cn + 1));

    float4 a0 = unpack4(in2[(size_t)n * 16 + l]);
    a0.x *= dn; a0.y *= dn; a0.z *= dn; a0.w *= dn;
    float4 a1 = make_float4(0.f, 0.f, 0.f, 0.f);
    float4 a2 = make_float4(0.f, 0.f, 0.f, 0.f);
    float4 a3 = make_float4(0.f, 0.f, 0.f, 0.f);

    if (deg > 0) {
        int   iA = (l < deg) ? l : 0;
        int   sA = bucket[(size_t)n * CAP + iA];
        float wA = rsqrtf((float)(cnt[sA] + 1));
        const int kmax = deg < 16 ? deg : 16;
        int k = 0;
        for (; k + 3 < kmax; k += 4) {
            int   s0 = __shfl(sA, k + 0, 16);
            int   s1 = __shfl(sA, k + 1, 16);
            int   s2 = __shfl(sA, k + 2, 16);
            int   s3 = __shfl(sA, k + 3, 16);
            float w0 = __shfl(wA, k + 0, 16);
            float w1 = __shfl(wA, k + 1, 16);
            float w2 = __shfl(wA, k + 2, 16);
            float w3 = __shfl(wA, k + 3, 16);
            float4 r0 = unpack4(in2[(size_t)s0 * 16 + l]);
            float4 r1 = unpack4(in2[(size_t)s1 * 16 + l]);
            float4 r2 = unpack4(in2[(size_t)s2 * 16 + l]);
            float4 r3 = unpack4(in2[(size_t)s3 * 16 + l]);
            a0.x = fmaf(w0, r0.x, a0.x); a0.y = fmaf(w0, r0.y, a0.y);
            a0.z = fmaf(w0, r0.z, a0.z); a0.w = fmaf(w0, r0.w, a0.w);
            a1.x = fmaf(w1, r1.x, a1.x); a1.y = fmaf(w1, r1.y, a1.y);
            a1.z = fmaf(w1, r1.z, a1.z); a1.w = fmaf(w1, r1.w, a1.w);
            a2.x = fmaf(w2, r2.x, a2.x); a2.y = fmaf(w2, r2.y, a2.y);
            a2.z = fmaf(w2, r2.z, a2.z); a2.w = fmaf(w2, r2.w, a2.w);
            a3.x = fmaf(w3, r3.x, a3.x); a3.y = fmaf(w3, r3.y, a3.y);
            a3.z = fmaf(w3, r3.z, a3.z); a3.w = fmaf(w3, r3.w, a3.w);
        }
        for (; k < kmax; ++k) {
            int   s0 = __shfl(sA, k, 16);
            float w0 = __shfl(wA, k, 16);
            float4 r0 = unpack4(in2[(size_t)s0 * 16 + l]);
            a0.x = fmaf(w0, r0.x, a0.x); a0.y = fmaf(w0, r0.y, a0.y);
            a0.z = fmaf(w0, r0.z, a0.z); a0.w = fmaf(w0, r0.w, a0.w);
        }
        if (deg > 16) {   // ~3% of nodes
            int   iB = (16 + l < deg) ? (16 + l) : 0;
            int   sB = bucket[(size_t)n * CAP + iB];
            float wB = rsqrtf((float)(cnt[sB] + 1));
            const int k2max = deg - 16;
            int k2 = 0;
            for (; k2 + 1 < k2max; k2 += 2) {
                int   s0 = __shfl(sB, k2 + 0, 16);
                int   s1 = __shfl(sB, k2 + 1, 16);
                float w0 = __shfl(wB, k2 + 0, 16);
                float w1 = __shfl(wB, k2 + 1, 16);
                float4 r0 = unpack4(in2[(size_t)s0 * 16 + l]);
                float4 r1 = unpack4(in2[(size_t)s1 * 16 + l]);
                a1.x = fmaf(w0, r0.x, a1.x); a1.y = fmaf(w0, r0.y, a1.y);
                a1.z = fmaf(w0, r0.z, a1.z); a1.w = fmaf(w0, r0.w, a1.w);
                a2.x = fmaf(w1, r1.x, a2.x); a2.y = fmaf(w1, r1.y, a2.y);
                a2.z = fmaf(w1, r1.z, a2.z); a2.w = fmaf(w1, r1.w, a2.w);
            }
            if (k2 < k2max) {
                int   s0 = __shfl(sB, k2, 16);
                float w0 = __shfl(wB, k2, 16);
                float4 r0 = unpack4(in2[(size_t)s0 * 16 + l]);
                a3.x = fmaf(w0, r0.x, a3.x); a3.y = fmaf(w0, r0.y, a3.y);
                a3.z = fmaf(w0, r0.z, a3.z); a3.w = fmaf(w0, r0.w, a3.w);
            }
        }
    }

    // inline overflow fixup (ovf_n is ~always 0; one hot scalar load)
    int m = *ovf_n;
    if (m > 0) {
        if (m > OVF_CAP) m = OVF_CAP;
        for (int i = 0; i < m; ++i) {
            int2 p = ovf[i];
            if (p.y == n) {
                float w = rsqrtf((float)(cnt[p.x] + 1));
                float4 r = unpack4(in2[(size_t)p.x * 16 + l]);
                a0.x = fmaf(w, r.x, a0.x); a0.y = fmaf(w, r.y, a0.y);
                a0.z = fmaf(w, r.z, a0.z); a0.w = fmaf(w, r.w, a0.w);
            }
        }
    }

    float4 r;
    r.x = dn * ((a0.x + a1.x) + (a2.x + a3.x));
    r.y = dn * ((a0.y + a1.y) + (a2.y + a3.y));
    r.z = dn * ((a0.z + a1.z) + (a2.z + a3.z));
    r.w = dn * ((a0.w + a1.w) + (a2.w + a3.w));
    if (F32OUT) {
        float4 bv = *(const float4*)&bias[4 * l];
        r.x += bv.x; r.y += bv.y; r.z += bv.z; r.w += bv.w;
        out4[(size_t)n * 16 + l] = r;
    } else {
        out2[(size_t)n * 16 + l] = pack4(r);
    }
}

__global__ __launch_bounds__(256) void k_gather_bf16(const uint2* __restrict__ in2,
                                                     const int* __restrict__ cnt,
                                                     const int* __restrict__ bucket,
                                                     const int* __restrict__ ovf_n,
                                                     const int2* __restrict__ ovf,
                                                     uint2* __restrict__ out2) {
    gather_body<false>(in2, cnt, bucket, ovf_n, ovf, nullptr, out2, nullptr);
}

__global__ __launch_bounds__(256) void k_gather_out(const uint2* __restrict__ in2,
                                                    const int* __restrict__ cnt,
                                                    const int* __restrict__ bucket,
                                                    const int* __restrict__ ovf_n,
                                                    const int2* __restrict__ ovf,
                                                    const float* __restrict__ bias,
                                                    float4* __restrict__ out4) {
    gather_body<true>(in2, cnt, bucket, ovf_n, ovf, bias, nullptr, out4);
}

// ======================= fallback path (atomic scatter, fp32) =======================

__global__ void k_init_deg(float* __restrict__ deg) {
    int n = blockIdx.x * blockDim.x + threadIdx.x;
    if (n < NN) deg[n] = 1.0f;
}
__global__ void k_count_deg(const int* __restrict__ dst, float* __restrict__ deg) {
    int e = blockIdx.x * blockDim.x + threadIdx.x;
    if (e < NE) atomicAdd(&deg[dst[e]], 1.0f);
}
__global__ void k_dinv_f(float* __restrict__ deg) {
    int n = blockIdx.x * blockDim.x + threadIdx.x;
    if (n < NN) deg[n] = rsqrtf(deg[n]);
}
__global__ void k_prop_init(const float* __restrict__ in, const float* __restrict__ dinv,
                            float* __restrict__ out) {
    int i = blockIdx.x * blockDim.x + threadIdx.x;
    if (i < NN * D) {
        int n = i >> 6;
        float di = dinv[n];
        out[i] = di * di * in[i];
    }
}
__global__ __launch_bounds__(256) void k_prop_edges(const float* __restrict__ in,
                                                    const int* __restrict__ src,
                                                    const int* __restrict__ dst,
                                                    const float* __restrict__ dinv,
                                                    float* __restrict__ out) {
    int t = blockIdx.x * blockDim.x + threadIdx.x;
    int e = t >> 6, f = t & 63;
    if (e < NE) {
        int s = src[e], d = dst[e];
        float w = dinv[s] * dinv[d];
        atomicAdd(&out[d * D + f], w * in[s * D + f]);
    }
}
__global__ __launch_bounds__(256) void k_linear(const float* __restrict__ in,
                                                const float* __restrict__ W,
                                                const float* __restrict__ bias,
                                                float* __restrict__ out) {
    __shared__ float Wt[64 * 65];
    __shared__ float rows[4][64];
    const int tid = threadIdx.x;
    for (int m = tid; m < 64 * 64; m += 256) {
        int o = m >> 6, i = m & 63;
        Wt[i * 65 + o] = W[m];
    }
    __syncthreads();
    const int wave = tid >> 6, lane = tid & 63;
    const float bo = bias[lane];
    for (int base = blockIdx.x * 4; base < NN; base += gridDim.x * 4) {
        int n = base + wave;
        if (n < NN) {
            rows[wave][lane] = in[n * D + lane];
            float acc = bo;
            #pragma unroll
            for (int i = 0; i < 64; ++i)
                acc = fmaf(rows[wave][i], Wt[i * 65 + lane], acc);
            out[n * D + lane] = acc;
        }
    }
}

// ======================= launch =======================

extern "C" void kernel_launch(void* const* d_in, const int* in_sizes, int n_in,
                              void* d_out, int out_size, void* d_ws, size_t ws_size,
                              hipStream_t stream) {
    const float* x   = (const float*)d_in[0];
    const int*   ei  = (const int*)d_in[1];
    const float* W   = (const float*)d_in[2];
    const float* b   = (const float*)d_in[3];
    float* out = (float*)d_out;

    const int* src = ei;        // edge_index[0]
    const int* dst = ei + NE;   // edge_index[1]

    char* ws = (char*)d_ws;
    size_t off = 0;
    auto take = [&](size_t bytes) -> char* {
        char* p = ws + off;
        off = (off + bytes + 255) & ~(size_t)255;
        return p;
    };

    int*            cnt    = (int*)take((size_t)NN * 4);
    int*            ovf_n  = (int*)take(256);                        // adjacent: one memset
    float*          dinv   = (float*)take((size_t)NN * 4);           // fallback only
    int2*           ovf    = (int2*)take((size_t)OVF_CAP * 8);
    unsigned short* P      = (unsigned short*)take((size_t)NN * 64 * 2);  // bf16 (12.8 MB)
    unsigned short* Q      = (unsigned short*)take((size_t)NN * 64 * 2);  // bf16 (12.8 MB)
    int*            bucket = (int*)take((size_t)NN * CAP * 4);
    float*          buf    = (float*)P;   // fallback fp32 buffer spans P+Q (25.6 MB)
    const bool use_bucket = (off <= ws_size);

    const int B = 256;
    const int gridE1 = (NE + B - 1) / B;   // 3907
    const int gridN1 = (NN + B - 1) / B;   // 391
    const int gridNW = NN / 16;            // 6250

    if (use_bucket) {
        size_t zlen = (size_t)((char*)ovf_n - (char*)cnt) + 256;
        (void)hipMemsetAsync(cnt, 0, zlen, stream);
        k_fill_bucket<<<FILL_NCHUNK * 8, B, 0, stream>>>(src, dst, cnt, bucket, ovf_n, ovf);
        k_cvt_linw<<<2048, B, 0, stream>>>(x, W, P);   // P = bf16(x @ W^T)
        // hop1: P -> Q
        k_gather_bf16<<<gridNW, B, 0, stream>>>((const uint2*)P, cnt, bucket, ovf_n, ovf, (uint2*)Q);
        // hop2: Q -> P
        k_gather_bf16<<<gridNW, B, 0, stream>>>((const uint2*)Q, cnt, bucket, ovf_n, ovf, (uint2*)P);
        // hop3: P -> out (fp32, + bias)
        k_gather_out<<<gridNW, B, 0, stream>>>((const uint2*)P, cnt, bucket, ovf_n, ovf, b, (float4*)out);
    } else {
        const int gridF = (NN * D + B - 1) / B;
        const int gridEW = (NE * 64) / B;
        k_init_deg <<<gridN1, B, 0, stream>>>(dinv);
        k_count_deg<<<gridE1, B, 0, stream>>>(dst, dinv);
        k_dinv_f   <<<gridN1, B, 0, stream>>>(dinv);
        k_prop_init <<<gridF, B, 0, stream>>>(x, dinv, buf);
        k_prop_edges<<<gridEW, B, 0, stream>>>(x, src, dst, dinv, buf);
        k_prop_init <<<gridF, B, 0, stream>>>(buf, dinv, out);
        k_prop_edges<<<gridEW, B, 0, stream>>>(buf, src, dst, dinv, out);
        k_prop_init <<<gridF, B, 0, stream>>>(out, dinv, buf);
        k_prop_edges<<<gridEW, B, 0, stream>>>(out, src, dst, dinv, buf);
        k_linear<<<NN / 4, B, 0, stream>>>(buf, W, b, out);
    }
}